// Round 1
// baseline (717.146 us; speedup 1.0000x reference)
//
#include <hip/hip_runtime.h>
#include <math.h>

// Problem constants: B=2, C=CIN=COUT=64, S=H=W=128, K=3, G=4 (groups are a no-op)
constexpr int HW   = 128 * 128;            // 16384
constexpr int NCHW = 2 * 64 * HW;          // 2097152

// Workspace layout (float element offsets). Z overlays q/k (dead by then),
// ftT overlays v, R overlays out2 (written later).
constexpr size_t OFF_Q    = 0;             // q   [2,64,128,128]
constexpr size_t OFF_K    = 2097152;       // k
constexpr size_t OFF_V    = 4194304;       // v   (later: ftT)
constexpr size_t OFF_FTT  = 4194304;       // ft transposed to [b,c,y,x]
constexpr size_t OFF_OUT  = 6291456;       // attention out
constexpr size_t OFF_OUT2 = 8388608;       // out2 (earlier: R intermediate)
constexpr size_t OFF_R    = 8388608;
constexpr size_t OFF_F    = 10485760;      // F[b,kh,kw] complex  (65536 floats)
constexpr size_t OFF_M    = 10551296;      // combined conv matrix (4096)
constexpr size_t OFF_BC   = 10555392;      // combined bias (64)
constexpr size_t OFF_Z    = 0;             // Z[b,c,kh,x] complex (4194304 floats)

// ---------------- generic 64x64 1x1-conv GEMM: y[b,co,p] = sum_ci w[co,ci] x[b,ci,p] (+bias) ----
__global__ __launch_bounds__(256) void k_gemm64(
    const float* __restrict__ x, const float* __restrict__ w,
    const float* __restrict__ bias, float* __restrict__ y)
{
    __shared__ float xs[64][64];   // [ci][px]
    __shared__ float wl[64][65];   // [co][ci] padded
    int blk = blockIdx.x;          // 2*256 blocks, 64 px each
    int b = blk >> 8;
    int px0 = (blk & 255) << 6;
    int t = threadIdx.x;
    for (int i = t; i < 4096; i += 256) {
        int r = i >> 6, cix = i & 63;
        wl[r][cix] = w[i];
        xs[r][cix] = x[b * (64 * HW) + r * HW + px0 + cix];
    }
    __syncthreads();
    int pxq = t & 15, rq = t >> 4;     // 4 px, 4 rows per thread
    float acc[4][4];
    #pragma unroll
    for (int i = 0; i < 4; i++)
        for (int j = 0; j < 4; j++) acc[i][j] = 0.f;
    for (int ci = 0; ci < 64; ci++) {
        float4 xv = *reinterpret_cast<const float4*>(&xs[ci][pxq * 4]);
        #pragma unroll
        for (int i = 0; i < 4; i++) {
            float wv = wl[rq * 4 + i][ci];
            acc[i][0] += wv * xv.x; acc[i][1] += wv * xv.y;
            acc[i][2] += wv * xv.z; acc[i][3] += wv * xv.w;
        }
    }
    #pragma unroll
    for (int i = 0; i < 4; i++) {
        int co = rq * 4 + i;
        float bb = bias ? bias[co] : 0.f;
        float* p = y + b * (64 * HW) + co * HW + px0 + pxq * 4;
        p[0] = acc[i][0] + bb; p[1] = acc[i][1] + bb;
        p[2] = acc[i][2] + bb; p[3] = acc[i][3] + bb;
    }
}

// ---------------- local 3x3 attention with rel-pos bias (zero-padded k,v; bias added after pad) --
__global__ __launch_bounds__(256) void k_attn(
    const float* __restrict__ q, const float* __restrict__ kc, const float* __restrict__ vc,
    const float* __restrict__ rel_h, const float* __restrict__ rel_w,
    float* __restrict__ out)
{
    int idx = blockIdx.x * 256 + threadIdx.x;     // [b,c,h,w] flat
    if (idx >= NCHW) return;
    int w = idx & 127;
    int h = (idx >> 7) & 127;
    int c = (idx >> 14) & 63;
    float qv = q[idx];
    float s[9], vv[9];
    #pragma unroll
    for (int ki = 0; ki < 3; ki++) {
        #pragma unroll
        for (int kj = 0; kj < 3; kj++) {
            int hh = h + ki - 1, ww = w + kj - 1;
            bool inb = (hh >= 0 && hh < 128 && ww >= 0 && ww < 128);
            int nidx = (idx & ~(HW - 1)) + hh * 128 + ww;
            float kvv = inb ? kc[nidx] : 0.f;
            float vvv = inb ? vc[nidx] : 0.f;
            float rel = (c < 32) ? rel_h[c * 3 + ki] : rel_w[(c - 32) * 3 + kj];
            s[ki * 3 + kj] = qv * (kvv + rel);
            vv[ki * 3 + kj] = vvv;
        }
    }
    float m = s[0];
    #pragma unroll
    for (int i = 1; i < 9; i++) m = fmaxf(m, s[i]);
    float den = 0.f, num = 0.f;
    #pragma unroll
    for (int i = 0; i < 9; i++) { float e = __expf(s[i] - m); den += e; num += e * vv[i]; }
    out[idx] = num / den;
}

// ---------------- ft [b,y,x,c] -> ftT [b,c,y,x] --------------------------------------------------
__global__ __launch_bounds__(256) void k_tft(const float* __restrict__ ft, float* __restrict__ ftT)
{
    __shared__ float tile[64][65];
    int blk = blockIdx.x; int b = blk >> 8; int p0 = (blk & 255) << 6;
    int t = threadIdx.x;
    for (int e = t; e < 4096; e += 256) {
        int pp = e >> 6, cc = e & 63;
        tile[pp][cc] = ft[(b * HW + p0 + pp) * 64 + cc];
    }
    __syncthreads();
    for (int e = t; e < 4096; e += 256) {
        int cc = e >> 6, pp = e & 63;
        ftT[b * (64 * HW) + cc * HW + p0 + pp] = tile[pp][cc];
    }
}

// ---------------- forward FFT of out[:,32]: row pass (over w), no scale --------------------------
__global__ __launch_bounds__(128) void k_fftrow_fwd(const float* __restrict__ out, float* __restrict__ R)
{
    int bh = blockIdx.x; int b = bh >> 7, h = bh & 127;   // grid 2*128
    int k = threadIdx.x;
    __shared__ float xr[128];
    xr[k] = out[((b * 64 + 32) << 14) + h * 128 + k];
    __syncthreads();
    float s0, c0; __sincosf(-6.2831853071795864769f * (float)k / 128.0f, &s0, &c0);
    float twr = 1.f, twi = 0.f, ar = 0.f, ai = 0.f;
    for (int n = 0; n < 128; n++) {
        float xv = xr[n];
        ar += xv * twr; ai += xv * twi;
        float nr = twr * c0 - twi * s0;
        twi = twr * s0 + twi * c0; twr = nr;
    }
    float2* Rp = (float2*)R;
    Rp[(b << 14) + h * 128 + k] = make_float2(ar, ai);
}

// ---------------- forward FFT col pass (over h), applies 1/128 ortho scale -----------------------
__global__ __launch_bounds__(128) void k_fftcol_fwd(const float* __restrict__ R, float* __restrict__ F)
{
    int bk = blockIdx.x; int b = bk >> 7, k2 = bk & 127;  // grid 2*128
    int k1 = threadIdx.x;
    __shared__ float2 col[128];
    const float2* Rp = (const float2*)R;
    col[k1] = Rp[(b << 14) + k1 * 128 + k2];
    __syncthreads();
    float s0, c0; __sincosf(-6.2831853071795864769f * (float)k1 / 128.0f, &s0, &c0);
    float twr = 1.f, twi = 0.f, ar = 0.f, ai = 0.f;
    for (int n = 0; n < 128; n++) {
        float2 xv = col[n];
        ar += xv.x * twr - xv.y * twi;
        ai += xv.x * twi + xv.y * twr;
        float nr = twr * c0 - twi * s0;
        twi = twr * s0 + twi * c0; twr = nr;
    }
    float2* Fp = (float2*)F;
    Fp[(b << 14) + k1 * 128 + k2] = make_float2(ar * (1.f / 128.f), ai * (1.f / 128.f));
}

// ---------------- combine conv chain: M = C1*W0*Cv ; bc = C1*(W0*cvb + w0b) + c1b ----------------
__global__ __launch_bounds__(256) void k_combine(
    const float* __restrict__ convv_w, const float* __restrict__ convv_b,
    const float* __restrict__ w0_w, const float* __restrict__ w0_b,
    const float* __restrict__ convv1_w, const float* __restrict__ convv1_b,
    float* __restrict__ M, float* __restrict__ bc)
{
    __shared__ float T[64][65];
    __shared__ float t2[64];
    int t = threadIdx.x;
    for (int e = t; e < 4096; e += 256) {
        int i = e >> 6, j = e & 63;
        float a = 0.f;
        for (int kk = 0; kk < 64; kk++) a += w0_w[i * 64 + kk] * convv_w[kk * 64 + j];
        T[i][j] = a;
    }
    if (t < 64) {
        float a = 0.f;
        for (int kk = 0; kk < 64; kk++) a += w0_w[t * 64 + kk] * convv_b[kk];
        t2[t] = a + w0_b[t];
    }
    __syncthreads();
    for (int e = t; e < 4096; e += 256) {
        int i = e >> 6, j = e & 63;
        float a = 0.f;
        for (int kk = 0; kk < 64; kk++) a += convv1_w[i * 64 + kk] * T[kk][j];
        M[e] = a;
    }
    if (t < 64) {
        float a = 0.f;
        for (int kk = 0; kk < 64; kk++) a += convv1_w[t * 64 + kk] * t2[kk];
        bc[t] = a + convv1_b[t];
    }
}

// ---------------- THE BIG ONE: wsum reduction (537 MB) + spectral multiply + inverse row DFT -----
// block = (c, h) over the frequency grid; Z[b,c,h,x] = sum_w F[b,h,w]*wsum[c,h,w] * e^{+2pi i wx/128}
__global__ __launch_bounds__(128) void k_wsum_ifftrow(
    const float* __restrict__ w1r, const float* __restrict__ w1i,
    const float* __restrict__ F, float* __restrict__ Z)
{
    int blk = blockIdx.x; int c = blk >> 7, h = blk & 127;   // grid 64*128
    int t = threadIdx.x;                                     // w, then k
    float sr = 0.f, si = 0.f;
    int base = (c << 20) + h * 128 + t;                      // c*64*HW + o*HW + h*128 + w
    #pragma unroll 8
    for (int o = 0; o < 64; o++) {
        sr += w1r[base + (o << 14)];
        si += w1i[base + (o << 14)];
    }
    __shared__ float4 g[128];                                // (b0r,b0i,b1r,b1i) per w
    const float2* Fp = (const float2*)F;
    float2 f0 = Fp[h * 128 + t];
    float2 f1 = Fp[(1 << 14) + h * 128 + t];
    g[t] = make_float4(f0.x * sr - f0.y * si, f0.x * si + f0.y * sr,
                       f1.x * sr - f1.y * si, f1.x * si + f1.y * sr);
    __syncthreads();
    float s0, c0; __sincosf(6.2831853071795864769f * (float)t / 128.0f, &s0, &c0); // + for inverse
    float twr = 1.f, twi = 0.f;
    float a0r = 0.f, a0i = 0.f, a1r = 0.f, a1i = 0.f;
    for (int n = 0; n < 128; n++) {
        float4 gv = g[n];
        a0r += gv.x * twr - gv.y * twi;
        a0i += gv.x * twi + gv.y * twr;
        a1r += gv.z * twr - gv.w * twi;
        a1i += gv.z * twi + gv.w * twr;
        float nr = twr * c0 - twi * s0;
        twi = twr * s0 + twi * c0; twr = nr;
    }
    float2* Zp = (float2*)Z;
    Zp[(c << 14) + h * 128 + t]               = make_float2(a0r, a0i);
    Zp[((64 + c) << 14) + h * 128 + t]        = make_float2(a1r, a1i);
}

// ---------------- inverse col DFT (real part only, i^h symmetry) + fused MSE reduction -----------
__global__ __launch_bounds__(256) void k_ifftcol_mse(
    const float* __restrict__ Zb, const float* __restrict__ out2,
    const float* __restrict__ ftT, const float* __restrict__ rate1,
    const float* __restrict__ rate2, float* __restrict__ result)
{
    int blk = blockIdx.x;            // b*256 + c*4 + xc
    int xc = blk & 3;
    int c  = (blk >> 2) & 63;
    int b  = blk >> 8;
    int t = threadIdx.x;
    int xl = t & 31;
    int yq = t >> 5;                 // 0..7
    __shared__ float2 zs[128][33];
    const float2* Zp = (const float2*)Zb;
    int zbase = ((b * 64 + c) << 14) + xc * 32;
    for (int e = t; e < 4096; e += 256) {
        int hh = e >> 5, xx = e & 31;
        zs[hh][xx] = Zp[zbase + hh * 128 + xx];
    }
    __syncthreads();

    // 4 base frequencies y0 = yq + 8j; derived y0+32m via i^h phase classes (h mod 4 buckets)
    float twx[4], twy[4], stx[4], sty[4];
    float Sr[4][4], Si[4][4];
    #pragma unroll
    for (int j = 0; j < 4; j++) {
        int y0 = yq + 8 * j;
        float ss, cc;
        __sincosf(6.2831853071795864769f * (float)y0 / 128.0f, &ss, &cc);
        stx[j] = cc; sty[j] = ss;
        twx[j] = 1.f; twy[j] = 0.f;
        #pragma unroll
        for (int m = 0; m < 4; m++) { Sr[j][m] = 0.f; Si[j][m] = 0.f; }
    }
    for (int h = 0; h < 128; h += 4) {
        #pragma unroll
        for (int m = 0; m < 4; m++) {
            float2 z = zs[h + m][xl];
            #pragma unroll
            for (int j = 0; j < 4; j++) {
                Sr[j][m] += z.x * twx[j] - z.y * twy[j];
                Si[j][m] += z.x * twy[j] + z.y * twx[j];
                float nr = twx[j] * stx[j] - twy[j] * sty[j];
                twy[j]   = twx[j] * sty[j] + twy[j] * stx[j];
                twx[j]   = nr;
            }
        }
    }
    float r1 = rate1[0], r2 = rate2[0];
    int x = xc * 32 + xl;
    int obase = ((b * 64 + c) << 14) + x;
    float part = 0.f;
    #pragma unroll
    for (int j = 0; j < 4; j++) {
        int y0 = yq + 8 * j;
        float o[4];
        o[0] = Sr[j][0] + Sr[j][1] + Sr[j][2] + Sr[j][3];
        o[1] = Sr[j][0] - Si[j][1] - Sr[j][2] + Si[j][3];
        o[2] = Sr[j][0] - Sr[j][1] + Sr[j][2] - Sr[j][3];
        o[3] = Sr[j][0] + Si[j][1] - Sr[j][2] - Si[j][3];
        #pragma unroll
        for (int m = 0; m < 4; m++) {
            int y = y0 + 32 * m;
            float out1 = o[m] * (1.f / 128.f);       // ifft2 ortho scale
            int gi = obase + y * 128;
            float mk = r1 * out1 + r2 * out2[gi];
            float d = mk - ftT[gi];
            part += d * d;
        }
    }
    __shared__ float red[256];
    red[t] = part;
    __syncthreads();
    for (int s = 128; s > 0; s >>= 1) {
        if (t < s) red[t] += red[t + s];
        __syncthreads();
    }
    if (t == 0) atomicAdd(result, red[0] * (1.f / 2097152.f));
}

extern "C" void kernel_launch(void* const* d_in, const int* in_sizes, int n_in,
                              void* d_out, int out_size, void* d_ws, size_t ws_size,
                              hipStream_t stream) {
    const float* fs       = (const float*)d_in[0];
    const float* ft       = (const float*)d_in[1];
    const float* w_q      = (const float*)d_in[2];
    const float* w_k      = (const float*)d_in[3];
    const float* w_v      = (const float*)d_in[4];
    const float* rel_h    = (const float*)d_in[5];
    const float* rel_w    = (const float*)d_in[6];
    const float* w1r      = (const float*)d_in[7];
    const float* w1i      = (const float*)d_in[8];
    const float* w0_w     = (const float*)d_in[9];
    const float* w0_b     = (const float*)d_in[10];
    const float* convv_w  = (const float*)d_in[11];
    const float* convv_b  = (const float*)d_in[12];
    const float* convv1_w = (const float*)d_in[13];
    const float* convv1_b = (const float*)d_in[14];
    const float* rate1    = (const float*)d_in[15];
    const float* rate2    = (const float*)d_in[16];

    float* ws = (float*)d_ws;
    float* q    = ws + OFF_Q;
    float* kk   = ws + OFF_K;
    float* vv   = ws + OFF_V;
    float* ftT  = ws + OFF_FTT;
    float* out  = ws + OFF_OUT;
    float* out2 = ws + OFF_OUT2;
    float* R    = ws + OFF_R;
    float* F    = ws + OFF_F;
    float* M    = ws + OFF_M;
    float* bc   = ws + OFF_BC;
    float* Z    = ws + OFF_Z;

    // q, k, v 1x1 convs
    k_gemm64<<<512, 256, 0, stream>>>(fs, w_q, nullptr, q);
    k_gemm64<<<512, 256, 0, stream>>>(fs, w_k, nullptr, kk);
    k_gemm64<<<512, 256, 0, stream>>>(fs, w_v, nullptr, vv);
    // 3x3 local attention -> out
    k_attn<<<8192, 256, 0, stream>>>(q, kk, vv, rel_h, rel_w, out);
    // ft transpose (v is dead now; ftT overlays it)
    k_tft<<<512, 256, 0, stream>>>(ft, ftT);
    // forward FFT of out channel 32 (R overlays out2 slot, free until conv chain below)
    k_fftrow_fwd<<<256, 128, 0, stream>>>(out, R);
    k_fftcol_fwd<<<256, 128, 0, stream>>>(R, F);
    // combined conv chain matrix, then out2 = M*out + bc
    k_combine<<<1, 256, 0, stream>>>(convv_w, convv_b, w0_w, w0_b, convv1_w, convv1_b, M, bc);
    k_gemm64<<<512, 256, 0, stream>>>(out, M, bc, out2);
    // fused wsum (537 MB HBM read) + spectral multiply + inverse row DFT (Z overlays q/k)
    k_wsum_ifftrow<<<8192, 128, 0, stream>>>(w1r, w1i, F, Z);
    // inverse col DFT + MSE
    hipMemsetAsync(d_out, 0, sizeof(float), stream);
    k_ifftcol_mse<<<512, 256, 0, stream>>>(Z, out2, ftT, rate1, rate2, (float*)d_out);
}

// Round 2
// 674.036 us; speedup vs baseline: 1.0640x; 1.0640x over previous
//
#include <hip/hip_runtime.h>
#include <math.h>

// Problem constants: B=2, C=CIN=COUT=64, S=H=W=128, K=3, G=4 (groups are a no-op)
constexpr int HW   = 128 * 128;            // 16384
constexpr int NCHW = 2 * 64 * HW;          // 2097152

// Workspace layout (float element offsets). Z overlays q/k (dead after attn),
// R overlays out2 (written later).
constexpr size_t OFF_Q    = 0;             // q   [2,64,128,128]
constexpr size_t OFF_K    = 2097152;       // k
constexpr size_t OFF_V    = 4194304;       // v
constexpr size_t OFF_OUT  = 6291456;       // attention out
constexpr size_t OFF_OUT2 = 8388608;       // out2 (earlier: R intermediate)
constexpr size_t OFF_R    = 8388608;
constexpr size_t OFF_F    = 10485760;      // F[b,kh,kw] complex  (65536 floats)
constexpr size_t OFF_M    = 10551296;      // combined conv matrix (4096)
constexpr size_t OFF_BC   = 10555392;      // combined bias (64)
constexpr size_t OFF_Z    = 0;             // Z[b,c,kh,x] complex (4194304 floats)

// ---------------- fused q,k,v 1x1 convs: one fs stage, 3 weight mats in LDS ---------------------
__global__ __launch_bounds__(256) void k_qkv(
    const float* __restrict__ fs,
    const float* __restrict__ w_q, const float* __restrict__ w_k, const float* __restrict__ w_v,
    float* __restrict__ q, float* __restrict__ kk, float* __restrict__ vv)
{
    __shared__ float xs[64][64];       // [ci][px]
    __shared__ float wl[3][64][65];    // [q/k/v][co][ci] padded
    int blk = blockIdx.x;              // 2*256 blocks, 64 px each
    int b = blk >> 8;
    int px0 = (blk & 255) << 6;
    int t = threadIdx.x;
    for (int i = t; i < 4096; i += 256) {
        int r = i >> 6, cix = i & 63;
        wl[0][r][cix] = w_q[i];
        wl[1][r][cix] = w_k[i];
        wl[2][r][cix] = w_v[i];
        xs[r][cix] = fs[b * (64 * HW) + r * HW + px0 + cix];
    }
    __syncthreads();
    int pxq = t & 15, rq = t >> 4;     // 4 px, 4 rows per thread
    float aq[4][4], ak[4][4], av[4][4];
    #pragma unroll
    for (int i = 0; i < 4; i++)
        for (int j = 0; j < 4; j++) { aq[i][j] = 0.f; ak[i][j] = 0.f; av[i][j] = 0.f; }
    for (int ci = 0; ci < 64; ci++) {
        float4 xv = *reinterpret_cast<const float4*>(&xs[ci][pxq * 4]);
        #pragma unroll
        for (int i = 0; i < 4; i++) {
            float wq_ = wl[0][rq * 4 + i][ci];
            float wk_ = wl[1][rq * 4 + i][ci];
            float wv_ = wl[2][rq * 4 + i][ci];
            aq[i][0] += wq_ * xv.x; aq[i][1] += wq_ * xv.y; aq[i][2] += wq_ * xv.z; aq[i][3] += wq_ * xv.w;
            ak[i][0] += wk_ * xv.x; ak[i][1] += wk_ * xv.y; ak[i][2] += wk_ * xv.z; ak[i][3] += wk_ * xv.w;
            av[i][0] += wv_ * xv.x; av[i][1] += wv_ * xv.y; av[i][2] += wv_ * xv.z; av[i][3] += wv_ * xv.w;
        }
    }
    #pragma unroll
    for (int i = 0; i < 4; i++) {
        int co = rq * 4 + i;
        size_t base = (size_t)b * (64 * HW) + (size_t)co * HW + px0 + pxq * 4;
        *reinterpret_cast<float4*>(q  + base) = make_float4(aq[i][0], aq[i][1], aq[i][2], aq[i][3]);
        *reinterpret_cast<float4*>(kk + base) = make_float4(ak[i][0], ak[i][1], ak[i][2], ak[i][3]);
        *reinterpret_cast<float4*>(vv + base) = make_float4(av[i][0], av[i][1], av[i][2], av[i][3]);
    }
}

// ---------------- generic 64x64 1x1-conv GEMM: y[b,co,p] = sum_ci w[co,ci] x[b,ci,p] (+bias) ----
__global__ __launch_bounds__(256) void k_gemm64(
    const float* __restrict__ x, const float* __restrict__ w,
    const float* __restrict__ bias, float* __restrict__ y)
{
    __shared__ float xs[64][64];   // [ci][px]
    __shared__ float wl[64][65];   // [co][ci] padded
    int blk = blockIdx.x;          // 2*256 blocks, 64 px each
    int b = blk >> 8;
    int px0 = (blk & 255) << 6;
    int t = threadIdx.x;
    for (int i = t; i < 4096; i += 256) {
        int r = i >> 6, cix = i & 63;
        wl[r][cix] = w[i];
        xs[r][cix] = x[b * (64 * HW) + r * HW + px0 + cix];
    }
    __syncthreads();
    int pxq = t & 15, rq = t >> 4;     // 4 px, 4 rows per thread
    float acc[4][4];
    #pragma unroll
    for (int i = 0; i < 4; i++)
        for (int j = 0; j < 4; j++) acc[i][j] = 0.f;
    for (int ci = 0; ci < 64; ci++) {
        float4 xv = *reinterpret_cast<const float4*>(&xs[ci][pxq * 4]);
        #pragma unroll
        for (int i = 0; i < 4; i++) {
            float wv = wl[rq * 4 + i][ci];
            acc[i][0] += wv * xv.x; acc[i][1] += wv * xv.y;
            acc[i][2] += wv * xv.z; acc[i][3] += wv * xv.w;
        }
    }
    #pragma unroll
    for (int i = 0; i < 4; i++) {
        int co = rq * 4 + i;
        float bb = bias ? bias[co] : 0.f;
        float* p = y + b * (64 * HW) + co * HW + px0 + pxq * 4;
        p[0] = acc[i][0] + bb; p[1] = acc[i][1] + bb;
        p[2] = acc[i][2] + bb; p[3] = acc[i][3] + bb;
    }
}

// ---------------- local 3x3 attention with rel-pos bias (zero-padded k,v; bias added after pad) --
__global__ __launch_bounds__(256) void k_attn(
    const float* __restrict__ q, const float* __restrict__ kc, const float* __restrict__ vc,
    const float* __restrict__ rel_h, const float* __restrict__ rel_w,
    float* __restrict__ out)
{
    int idx = blockIdx.x * 256 + threadIdx.x;     // [b,c,h,w] flat
    if (idx >= NCHW) return;
    int w = idx & 127;
    int h = (idx >> 7) & 127;
    int c = (idx >> 14) & 63;
    float qv = q[idx];
    float s[9], vv[9];
    #pragma unroll
    for (int ki = 0; ki < 3; ki++) {
        #pragma unroll
        for (int kj = 0; kj < 3; kj++) {
            int hh = h + ki - 1, ww = w + kj - 1;
            bool inb = (hh >= 0 && hh < 128 && ww >= 0 && ww < 128);
            int nidx = (idx & ~(HW - 1)) + hh * 128 + ww;
            float kvv = inb ? kc[nidx] : 0.f;
            float vvv = inb ? vc[nidx] : 0.f;
            float rel = (c < 32) ? rel_h[c * 3 + ki] : rel_w[(c - 32) * 3 + kj];
            s[ki * 3 + kj] = qv * (kvv + rel);
            vv[ki * 3 + kj] = vvv;
        }
    }
    float m = s[0];
    #pragma unroll
    for (int i = 1; i < 9; i++) m = fmaxf(m, s[i]);
    float den = 0.f, num = 0.f;
    #pragma unroll
    for (int i = 0; i < 9; i++) { float e = __expf(s[i] - m); den += e; num += e * vv[i]; }
    out[idx] = num / den;
}

// ---------------- forward FFT of out[:,32]: row pass (over w), no scale --------------------------
__global__ __launch_bounds__(128) void k_fftrow_fwd(const float* __restrict__ out, float* __restrict__ R)
{
    int bh = blockIdx.x; int b = bh >> 7, h = bh & 127;   // grid 2*128
    int k = threadIdx.x;
    __shared__ float xr[128];
    xr[k] = out[((b * 64 + 32) << 14) + h * 128 + k];
    __syncthreads();
    float s0, c0; __sincosf(-6.2831853071795864769f * (float)k / 128.0f, &s0, &c0);
    float twr = 1.f, twi = 0.f, ar = 0.f, ai = 0.f;
    for (int n = 0; n < 128; n++) {
        float xv = xr[n];
        ar += xv * twr; ai += xv * twi;
        float nr = twr * c0 - twi * s0;
        twi = twr * s0 + twi * c0; twr = nr;
    }
    float2* Rp = (float2*)R;
    Rp[(b << 14) + h * 128 + k] = make_float2(ar, ai);
}

// ---------------- forward FFT col pass (over h), applies 1/128 ortho scale -----------------------
__global__ __launch_bounds__(128) void k_fftcol_fwd(const float* __restrict__ R, float* __restrict__ F)
{
    int bk = blockIdx.x; int b = bk >> 7, k2 = bk & 127;  // grid 2*128
    int k1 = threadIdx.x;
    __shared__ float2 col[128];
    const float2* Rp = (const float2*)R;
    col[k1] = Rp[(b << 14) + k1 * 128 + k2];
    __syncthreads();
    float s0, c0; __sincosf(-6.2831853071795864769f * (float)k1 / 128.0f, &s0, &c0);
    float twr = 1.f, twi = 0.f, ar = 0.f, ai = 0.f;
    for (int n = 0; n < 128; n++) {
        float2 xv = col[n];
        ar += xv.x * twr - xv.y * twi;
        ai += xv.x * twi + xv.y * twr;
        float nr = twr * c0 - twi * s0;
        twi = twr * s0 + twi * c0; twr = nr;
    }
    float2* Fp = (float2*)F;
    Fp[(b << 14) + k1 * 128 + k2] = make_float2(ar * (1.f / 128.f), ai * (1.f / 128.f));
}

// ---------------- combine conv chain: M = C1*W0*Cv ; bc = C1*(W0*cvb + w0b) + c1b ----------------
// LDS-staged (round-1 version latency-bound on global scalar loads from ONE CU).
__global__ __launch_bounds__(256) void k_combine(
    const float* __restrict__ convv_w, const float* __restrict__ convv_b,
    const float* __restrict__ w0_w, const float* __restrict__ w0_b,
    const float* __restrict__ convv1_w, const float* __restrict__ convv1_b,
    float* __restrict__ M, float* __restrict__ bc)
{
    __shared__ float A[64][64];    // convv_w
    __shared__ float Bm[64][64];   // w0_w
    __shared__ float Cm[64][64];   // convv1_w
    __shared__ float T[64][65];
    __shared__ float t2[64];
    int t = threadIdx.x;
    for (int e = t; e < 4096; e += 256) {
        int i = e >> 6, j = e & 63;
        A[i][j]  = convv_w[e];
        Bm[i][j] = w0_w[e];
        Cm[i][j] = convv1_w[e];
    }
    __syncthreads();
    for (int e = t; e < 4096; e += 256) {
        int i = e >> 6, j = e & 63;
        float a = 0.f;
        for (int kk = 0; kk < 64; kk++) a += Bm[i][kk] * A[kk][j];
        T[i][j] = a;
    }
    if (t < 64) {
        float a = 0.f;
        for (int kk = 0; kk < 64; kk++) a += Bm[t][kk] * convv_b[kk];
        t2[t] = a + w0_b[t];
    }
    __syncthreads();
    for (int e = t; e < 4096; e += 256) {
        int i = e >> 6, j = e & 63;
        float a = 0.f;
        for (int kk = 0; kk < 64; kk++) a += Cm[i][kk] * T[kk][j];
        M[e] = a;
    }
    if (t < 64) {
        float a = 0.f;
        for (int kk = 0; kk < 64; kk++) a += Cm[t][kk] * t2[kk];
        bc[t] = a + convv1_b[t];
    }
}

// ---------------- THE BIG ONE: wsum reduction (537 MB) + spectral multiply + inverse row DFT -----
// Vectorized: thread (wq = w/4, og = o-group of 16) does float4 loads; LDS reduce across og;
// then per-thread row iDFT exactly as before.
__global__ __launch_bounds__(128) void k_wsum_ifftrow(
    const float* __restrict__ w1r, const float* __restrict__ w1i,
    const float* __restrict__ F, float* __restrict__ Z)
{
    int blk = blockIdx.x; int c = blk >> 7, h = blk & 127;   // grid 64*128
    int t = threadIdx.x;
    int wq = t & 31, og = t >> 5;    // wq: float4 chunk of w; og: 16-o group
    const float4* r4 = (const float4*)(w1r + ((size_t)c << 20) + (h << 7));
    const float4* i4 = (const float4*)(w1i + ((size_t)c << 20) + (h << 7));
    float4 sr = make_float4(0.f, 0.f, 0.f, 0.f);
    float4 si = make_float4(0.f, 0.f, 0.f, 0.f);
    int base = ((og * 16) << 12) + wq;                       // float4 index; o-stride = 4096
    #pragma unroll 8
    for (int oo = 0; oo < 16; oo++) {
        float4 a = r4[base + (oo << 12)];
        float4 bb = i4[base + (oo << 12)];
        sr.x += a.x;  sr.y += a.y;  sr.z += a.z;  sr.w += a.w;
        si.x += bb.x; si.y += bb.y; si.z += bb.z; si.w += bb.w;
    }
    __shared__ float4 redr[4][32];
    __shared__ float4 redi[4][32];
    __shared__ float2 g0[128];
    __shared__ float2 g1[128];
    redr[og][wq] = sr; redi[og][wq] = si;
    __syncthreads();
    if (t < 32) {
        float4 r0 = redr[0][t], r1_ = redr[1][t], r2_ = redr[2][t], r3 = redr[3][t];
        float4 i0 = redi[0][t], i1 = redi[1][t], i2 = redi[2][t], i3 = redi[3][t];
        float sumr[4], sumi[4];
        sumr[0] = r0.x + r1_.x + r2_.x + r3.x;
        sumr[1] = r0.y + r1_.y + r2_.y + r3.y;
        sumr[2] = r0.z + r1_.z + r2_.z + r3.z;
        sumr[3] = r0.w + r1_.w + r2_.w + r3.w;
        sumi[0] = i0.x + i1.x + i2.x + i3.x;
        sumi[1] = i0.y + i1.y + i2.y + i3.y;
        sumi[2] = i0.z + i1.z + i2.z + i3.z;
        sumi[3] = i0.w + i1.w + i2.w + i3.w;
        const float2* Fp = (const float2*)F;
        #pragma unroll
        for (int j = 0; j < 4; j++) {
            int w = t * 4 + j;
            float wr = sumr[j], wi = sumi[j];
            float2 f0 = Fp[(h << 7) + w];
            float2 f1 = Fp[(1 << 14) + (h << 7) + w];
            g0[w] = make_float2(f0.x * wr - f0.y * wi, f0.x * wi + f0.y * wr);
            g1[w] = make_float2(f1.x * wr - f1.y * wi, f1.x * wi + f1.y * wr);
        }
    }
    __syncthreads();
    float s0, c0; __sincosf(6.2831853071795864769f * (float)t / 128.0f, &s0, &c0); // + for inverse
    float twr = 1.f, twi = 0.f;
    float a0r = 0.f, a0i = 0.f, a1r = 0.f, a1i = 0.f;
    for (int n = 0; n < 128; n++) {
        float2 u0 = g0[n];
        float2 u1 = g1[n];
        a0r += u0.x * twr - u0.y * twi;
        a0i += u0.x * twi + u0.y * twr;
        a1r += u1.x * twr - u1.y * twi;
        a1i += u1.x * twi + u1.y * twr;
        float nr = twr * c0 - twi * s0;
        twi = twr * s0 + twi * c0; twr = nr;
    }
    float2* Zp = (float2*)Z;
    Zp[(c << 14) + h * 128 + t]        = make_float2(a0r, a0i);
    Zp[((64 + c) << 14) + h * 128 + t] = make_float2(a1r, a1i);
}

// ---------------- inverse col DFT (real part only, i^h symmetry) + fused MSE reduction -----------
// Reads ft directly in [b,y,x,c] layout (no transpose kernel; L2/L3 absorb the strided reads).
__global__ __launch_bounds__(256) void k_ifftcol_mse(
    const float* __restrict__ Zb, const float* __restrict__ out2,
    const float* __restrict__ ft, const float* __restrict__ rate1,
    const float* __restrict__ rate2, float* __restrict__ result)
{
    int blk = blockIdx.x;            // b*256 + c*4 + xc
    int xc = blk & 3;
    int c  = (blk >> 2) & 63;
    int b  = blk >> 8;
    int t = threadIdx.x;
    int xl = t & 31;
    int yq = t >> 5;                 // 0..7
    __shared__ float2 zs[128][33];
    const float2* Zp = (const float2*)Zb;
    int zbase = ((b * 64 + c) << 14) + xc * 32;
    for (int e = t; e < 4096; e += 256) {
        int hh = e >> 5, xx = e & 31;
        zs[hh][xx] = Zp[zbase + hh * 128 + xx];
    }
    __syncthreads();

    // 4 base frequencies y0 = yq + 8j; derived y0+32m via i^h phase classes (h mod 4 buckets)
    float twx[4], twy[4], stx[4], sty[4];
    float Sr[4][4], Si[4][4];
    #pragma unroll
    for (int j = 0; j < 4; j++) {
        int y0 = yq + 8 * j;
        float ss, cc;
        __sincosf(6.2831853071795864769f * (float)y0 / 128.0f, &ss, &cc);
        stx[j] = cc; sty[j] = ss;
        twx[j] = 1.f; twy[j] = 0.f;
        #pragma unroll
        for (int m = 0; m < 4; m++) { Sr[j][m] = 0.f; Si[j][m] = 0.f; }
    }
    for (int h = 0; h < 128; h += 4) {
        #pragma unroll
        for (int m = 0; m < 4; m++) {
            float2 z = zs[h + m][xl];
            #pragma unroll
            for (int j = 0; j < 4; j++) {
                Sr[j][m] += z.x * twx[j] - z.y * twy[j];
                Si[j][m] += z.x * twy[j] + z.y * twx[j];
                float nr = twx[j] * stx[j] - twy[j] * sty[j];
                twy[j]   = twx[j] * sty[j] + twy[j] * stx[j];
                twx[j]   = nr;
            }
        }
    }
    float r1 = rate1[0], r2 = rate2[0];
    int x = xc * 32 + xl;
    int obase = ((b * 64 + c) << 14) + x;
    float part = 0.f;
    #pragma unroll
    for (int j = 0; j < 4; j++) {
        int y0 = yq + 8 * j;
        float o[4];
        o[0] = Sr[j][0] + Sr[j][1] + Sr[j][2] + Sr[j][3];
        o[1] = Sr[j][0] - Si[j][1] - Sr[j][2] + Si[j][3];
        o[2] = Sr[j][0] - Sr[j][1] + Sr[j][2] - Sr[j][3];
        o[3] = Sr[j][0] + Si[j][1] - Sr[j][2] - Si[j][3];
        #pragma unroll
        for (int m = 0; m < 4; m++) {
            int y = y0 + 32 * m;
            float out1 = o[m] * (1.f / 128.f);       // ifft2 ortho scale
            int gi = obase + y * 128;
            float mk = r1 * out1 + r2 * out2[gi];
            int fidx = ((b * HW + y * 128 + x) << 6) + c;
            float d = mk - ft[fidx];
            part += d * d;
        }
    }
    __shared__ float red[256];
    red[t] = part;
    __syncthreads();
    for (int s = 128; s > 0; s >>= 1) {
        if (t < s) red[t] += red[t + s];
        __syncthreads();
    }
    if (t == 0) atomicAdd(result, red[0] * (1.f / 2097152.f));
}

extern "C" void kernel_launch(void* const* d_in, const int* in_sizes, int n_in,
                              void* d_out, int out_size, void* d_ws, size_t ws_size,
                              hipStream_t stream) {
    const float* fs       = (const float*)d_in[0];
    const float* ft       = (const float*)d_in[1];
    const float* w_q      = (const float*)d_in[2];
    const float* w_k      = (const float*)d_in[3];
    const float* w_v      = (const float*)d_in[4];
    const float* rel_h    = (const float*)d_in[5];
    const float* rel_w    = (const float*)d_in[6];
    const float* w1r      = (const float*)d_in[7];
    const float* w1i      = (const float*)d_in[8];
    const float* w0_w     = (const float*)d_in[9];
    const float* w0_b     = (const float*)d_in[10];
    const float* convv_w  = (const float*)d_in[11];
    const float* convv_b  = (const float*)d_in[12];
    const float* convv1_w = (const float*)d_in[13];
    const float* convv1_b = (const float*)d_in[14];
    const float* rate1    = (const float*)d_in[15];
    const float* rate2    = (const float*)d_in[16];

    float* ws = (float*)d_ws;
    float* q    = ws + OFF_Q;
    float* kk   = ws + OFF_K;
    float* vv   = ws + OFF_V;
    float* out  = ws + OFF_OUT;
    float* out2 = ws + OFF_OUT2;
    float* R    = ws + OFF_R;
    float* F    = ws + OFF_F;
    float* M    = ws + OFF_M;
    float* bc   = ws + OFF_BC;
    float* Z    = ws + OFF_Z;

    // fused q,k,v 1x1 convs
    k_qkv<<<512, 256, 0, stream>>>(fs, w_q, w_k, w_v, q, kk, vv);
    // 3x3 local attention -> out
    k_attn<<<8192, 256, 0, stream>>>(q, kk, vv, rel_h, rel_w, out);
    // forward FFT of out channel 32 (R overlays out2 slot, free until conv chain below)
    k_fftrow_fwd<<<256, 128, 0, stream>>>(out, R);
    k_fftcol_fwd<<<256, 128, 0, stream>>>(R, F);
    // combined conv chain matrix, then out2 = M*out + bc
    k_combine<<<1, 256, 0, stream>>>(convv_w, convv_b, w0_w, w0_b, convv1_w, convv1_b, M, bc);
    k_gemm64<<<512, 256, 0, stream>>>(out, M, bc, out2);
    // fused wsum (537 MB HBM read) + spectral multiply + inverse row DFT (Z overlays q/k)
    k_wsum_ifftrow<<<8192, 128, 0, stream>>>(w1r, w1i, F, Z);
    // inverse col DFT + MSE (reads ft directly)
    hipMemsetAsync(d_out, 0, sizeof(float), stream);
    k_ifftcol_mse<<<512, 256, 0, stream>>>(Z, out2, ft, rate1, rate2, (float*)d_out);
}